// Round 12
// baseline (219.589 us; speedup 1.0000x reference)
//
#include <hip/hip_runtime.h>

#define N_NODE 100000
#define N_PAD  100064            // padded rows for OOB-safe fragment loads
#define N_EDGE 1000000
#define HID 64
#define ATTN 32
#define REL_VOCAB 2005

#define CBSHIFT 9
#define CBN    512               // nodes per coarse bucket
#define NCB    196               // ceil(N_NODE/CBN)
#define MAXCB  8192              // slots per bucket region (mean 5120, +43σ)
#define LCAP   6400              // LDS sort capacity (mean +18σ)
#define N_SLOT (NCB*MAXCB)       // 1,605,632 padded slots
#define ACHUNK 4096              // edges per k_part block

typedef short  bf16x8 __attribute__((ext_vector_type(8)));
typedef float  f32x4  __attribute__((ext_vector_type(4)));

__device__ __forceinline__ float sigf(float x){ return 1.0f/(1.0f+__expf(-x)); }
__device__ __forceinline__ float bf2f(unsigned short u){
  return __uint_as_float(((unsigned int)u) << 16);
}
__device__ __forceinline__ unsigned short f2bf(float f){  // RNE
  unsigned int x = __float_as_uint(f);
  x += 0x7fffu + ((x >> 16) & 1u);
  return (unsigned short)(x >> 16);
}
__device__ __forceinline__ bf16x8 pk8(float4 a, float4 b){
  bf16x8 r;
  r[0]=(short)f2bf(a.x); r[1]=(short)f2bf(a.y);
  r[2]=(short)f2bf(a.z); r[3]=(short)f2bf(a.w);
  r[4]=(short)f2bf(b.x); r[5]=(short)f2bf(b.y);
  r[6]=(short)f2bf(b.z); r[7]=(short)f2bf(b.w);
  return r;
}

__device__ __forceinline__ float dot64(const float4* a, const float4* __restrict__ w){
  float s0=0.f,s1=0.f,s2=0.f,s3=0.f;
  #pragma unroll
  for (int i=0;i<16;i++){
    float4 av=a[i]; float4 wv=w[i];
    s0=fmaf(av.x,wv.x,s0); s1=fmaf(av.y,wv.y,s1);
    s2=fmaf(av.z,wv.z,s2); s3=fmaf(av.w,wv.w,s3);
  }
  return (s0+s1)+(s2+s3);
}

// ---- per-relation precompute, wave-parallel: one wave per relation ----
__global__ void __launch_bounds__(256, 4) k_pre(
    const float* __restrict__ re, const float* __restrict__ Wr,
    const float* __restrict__ ww, const float* __restrict__ wb,
    unsigned short* __restrict__ srel16, unsigned short* __restrict__ re16,
    float* __restrict__ hrW1)
{
  int w = (blockIdx.x*blockDim.x + threadIdx.x) >> 6;
  int l = threadIdx.x & 63;
  if (w >= REL_VOCAB) return;
  const int r = w;
  const int j = l & 31;
  const bool hi = (l >= 32);

  float4 ev[16];
  const float4* ep = (const float4*)(re + (size_t)(hi ? REL_VOCAB + r : r)*HID);
  #pragma unroll
  for (int i=0;i<16;i++) ev[i]=ep[i];

  const float4* wrow = (const float4*)(Wr + (size_t)(hi ? ATTN + j : j)*HID);
  float d = dot64(ev, wrow);

  if (hi) hrW1[r*ATTN + j] = d;

  float p = hi ? 0.f : fmaxf(d, 0.f) * ww[j];
  p += __shfl_xor(p, 1);
  p += __shfl_xor(p, 2);
  p += __shfl_xor(p, 4);
  p += __shfl_xor(p, 8);
  p += __shfl_xor(p, 16);
  p += __shfl_xor(p, 32);
  float alpha = sigf(p + wb[0]);

  float e0l = re[(size_t)r*HID + l];
  float e1l = re[(size_t)(REL_VOCAB + r)*HID + l];
  srel16[r*HID + l] = f2bf(alpha * e0l);
  re16[r*HID + l]   = f2bf(e1l);
}

__global__ void k_izero(int* __restrict__ p, int n){
  int i = blockIdx.x*blockDim.x + threadIdx.x;
  if (i < n) p[i] = 0;
}

__global__ void k_zero4(float4* __restrict__ p, int n4){
  int i = blockIdx.x*blockDim.x + threadIdx.x;
  if (i < n4) p[i] = make_float4(0.f,0.f,0.f,0.f);
}

// ---- weight pack into bf16 MFMA B-fragment order ----
__global__ void k_wt(const float* __restrict__ Wh, const float* __restrict__ Wih,
                     const float* __restrict__ Whh, const float* __restrict__ Ws,
                     unsigned short* __restrict__ pkWh, unsigned short* __restrict__ pkWih,
                     unsigned short* __restrict__ pkWhh, unsigned short* __restrict__ pkWs)
{
  int tid = blockIdx.x*blockDim.x + threadIdx.x;
  if (tid >= 116*64) return;
  int rec = tid >> 6, l = tid & 63;
  const float* src; unsigned short* dst; int tile, c;
  if (rec < 16){
    int li = rec >> 3, q = rec & 7; tile = q >> 1; c = q & 1;
    src = Wh + li*4096;
    dst = pkWh + (size_t)((li*8 + q)*64 + l)*8;
  } else if (rec < 64){
    int q2 = rec - 16; int li = q2 / 24, q = q2 % 24; tile = q >> 1; c = q & 1;
    src = Wih + li*12288;
    dst = pkWih + (size_t)((li*24 + q)*64 + l)*8;
  } else if (rec < 112){
    int q2 = rec - 64; int li = q2 / 24, q = q2 % 24; tile = q >> 1; c = q & 1;
    src = Whh + li*12288;
    dst = pkWhh + (size_t)((li*24 + q)*64 + l)*8;
  } else {
    int q = rec - 112; tile = q >> 1; c = q & 1;
    src = Ws + ATTN*HID;                       // layer-1 Ws only
    dst = pkWs + (size_t)(q*64 + l)*8;
  }
  int row = tile*16 + (l&15);
  int k0  = c*32 + (l>>4)*8;
  #pragma unroll
  for (int j=0;j<8;j++) dst[j] = f2bf(src[row*64 + k0 + j]);
}

// ---- pass A: block-level partition into 196 coarse buckets ----
__global__ void __launch_bounds__(256, 4) k_part(
    const int* __restrict__ edges, int* __restrict__ gcursor,
    uint2* __restrict__ tmp)
{
  __shared__ int hcnt[NCB];
  __shared__ int hbase[NCB];
  __shared__ int hcur[NCB];
  const int t = threadIdx.x;
  const int base = blockIdx.x * ACHUNK;
  const int nE = min(ACHUNK, N_EDGE - base);

  if (t < NCB){ hcnt[t] = 0; }
  __syncthreads();

  unsigned pk[16]; int bb[16], lo[16];
  const int2* e2 = (const int2*)edges;
  #pragma unroll
  for (int j=0;j<16;j++){
    int idx = j*256 + t;
    if (idx < nE){
      int e = base + idx;
      int rel = e2[e*3+1].x;
      int2 so = e2[e*3+2];
      pk[j] = ((unsigned)rel << 17) | (unsigned)so.x;
      bb[j] = so.y >> CBSHIFT;
      lo[j] = so.y & (CBN-1);
      atomicAdd(&hcnt[bb[j]], 1);
    } else bb[j] = -1;
  }
  __syncthreads();
  if (t < NCB){
    hbase[t] = (hcnt[t] > 0) ? atomicAdd(&gcursor[t], hcnt[t]) : 0;
    hcur[t] = 0;
  }
  __syncthreads();
  #pragma unroll
  for (int j=0;j<16;j++){
    if (bb[j] >= 0){
      int pos = hbase[bb[j]] + atomicAdd(&hcur[bb[j]], 1);
      if (pos < MAXCB)
        tmp[(size_t)bb[j]*MAXCB + pos] = make_uint2(pk[j], (unsigned)lo[j]);
    }
  }
}

// ---- pass B: in-bucket counting sort, one block per coarse bucket ----
// outputs packed pairP (4B/edge), nodeS (2B/edge, local node id), start/end.
__global__ void __launch_bounds__(256, 2) k_bsort2(
    const uint2* __restrict__ tmp, const int* __restrict__ gcursor,
    unsigned int* __restrict__ pairP, unsigned short* __restrict__ nodeS,
    int* __restrict__ startArr, int* __restrict__ endArr)
{
  __shared__ int lcnt[CBN];
  __shared__ int lsc[CBN];
  __shared__ int lcur[CBN];
  __shared__ uint2 lout[LCAP];
  const int b = blockIdx.x, t = threadIdx.x;
  const int base = b*MAXCB;
  const int size = min(gcursor[b], LCAP);

  lcnt[t] = 0; lcnt[256+t] = 0;
  __syncthreads();
  for (int i=t; i<size; i+=256)
    atomicAdd(&lcnt[tmp[base+i].y], 1);
  __syncthreads();

  int cA = lcnt[t], cB = lcnt[256+t];
  lsc[t] = cA; lsc[256+t] = cB;
  __syncthreads();
  #pragma unroll
  for (int off=1; off<256; off<<=1){
    int vA = (t>=off) ? lsc[t-off] : 0;
    int vB = (t>=off) ? lsc[256+t-off] : 0;
    __syncthreads();
    lsc[t] += vA; lsc[256+t] += vB;
    __syncthreads();
  }
  int totA = lsc[255];
  __syncthreads();
  lsc[256+t] += totA;
  __syncthreads();

  {
    int inclA = lsc[t], exclA = inclA - cA;
    lcur[t] = exclA;
    int n = b*CBN + t;
    if (n < N_NODE){ startArr[n] = base + exclA; endArr[n] = base + inclA; }
    int inclB = lsc[256+t], exclB = inclB - cB;
    lcur[256+t] = exclB;
    int n2 = b*CBN + 256 + t;
    if (n2 < N_NODE){ startArr[n2] = base + exclB; endArr[n2] = base + inclB; }
  }
  __syncthreads();

  for (int i=t; i<size; i+=256){
    uint2 p = tmp[base+i];
    int pos = atomicAdd(&lcur[p.y], 1);
    lout[pos] = p;
  }
  __syncthreads();
  for (int i=t; i<size; i+=256){
    uint2 q = lout[i];
    pairP[base+i] = q.x;
    nodeS[base+i] = (unsigned short)q.y;
  }
}

// ---- layer-0 aggregation: wave per node (bf16 table) -> bf16 agg ----
__global__ void k_agg0(const int* __restrict__ startArr, const int* __restrict__ endArr,
                       const unsigned int* __restrict__ pairP,
                       const unsigned short* __restrict__ srel16,
                       unsigned short* __restrict__ agg16)
{
  int t = blockIdx.x*blockDim.x + threadIdx.x;
  int n = __builtin_amdgcn_readfirstlane(t >> 6);
  int k = t & 63;
  if (n >= N_NODE) return;
  int b = startArr[n], e_ = endArr[n];
  float acc = 0.f;
  int i = b;
  for (; i+3 < e_; i += 4){
    int r0=pairP[i]>>17, r1=pairP[i+1]>>17, r2=pairP[i+2]>>17, r3=pairP[i+3]>>17;
    float v0=bf2f(srel16[r0*HID+k]), v1=bf2f(srel16[r1*HID+k]);
    float v2=bf2f(srel16[r2*HID+k]), v3=bf2f(srel16[r3*HID+k]);
    acc += v0; acc += v1; acc += v2; acc += v3;
  }
  for (; i < e_; ++i) acc += bf2f(srel16[(pairP[i]>>17)*HID + k]);
  agg16[(size_t)n*HID + k] = f2bf(acc);
}

// ---- fused layer-1 edge phase: alpha (MFMA) + segmented aggregate ----
// wave = 16 slots. Phase 1: alpha via mfma_16x16x32 (h16 rows as A-frags).
// Phase 2: lane k owns channel k; serial walk over the 16 slots reusing the
// L1-hot h16 rows; flush per obj-segment via fp32 atomicAdd (agg32 zeroed).
__global__ void __launch_bounds__(256, 4) k_fuse1(
    const unsigned int* __restrict__ pairP, const unsigned short* __restrict__ nodeS,
    const int* __restrict__ gcursor, const unsigned short* __restrict__ h16,
    const float* __restrict__ hrW1, const unsigned short* __restrict__ pkWs,
    const float* __restrict__ ww1, const float* __restrict__ wb1,
    const unsigned short* __restrict__ re16, float* __restrict__ agg32)
{
  const int t = threadIdx.x;
  const int w = t >> 6, l = t & 63;
  const int lr = l & 15, lg = l >> 4;
  const int i0 = (blockIdx.x*4 + w) * 16;      // N_SLOT = 64 * gridDim
  const int bkt   = i0 >> 13;                  // MAXCB = 8192 slots/bucket
  const int local = i0 & (MAXCB-1);
  const int size  = min(gcursor[bkt], LCAP);
  if (local >= size) return;                   // wave-uniform
  const int nv = min(16, size - local);

  unsigned pe = pairP[i0 + lr];
  int ns = (int)nodeS[i0 + lr];
  int subA = (int)(pe & 0x1FFFFu);
  bf16x8 a0 = *(const bf16x8*)(h16 + (size_t)subA*HID + lg*8);
  bf16x8 a1 = *(const bf16x8*)(h16 + (size_t)subA*HID + 32 + lg*8);

  bf16x8 b00 = *(const bf16x8*)(pkWs + (size_t)(0*64 + l)*8);
  bf16x8 b01 = *(const bf16x8*)(pkWs + (size_t)(1*64 + l)*8);
  bf16x8 b10 = *(const bf16x8*)(pkWs + (size_t)(2*64 + l)*8);
  bf16x8 b11 = *(const bf16x8*)(pkWs + (size_t)(3*64 + l)*8);

  f32x4 acc0 = {0.f,0.f,0.f,0.f}, acc1 = {0.f,0.f,0.f,0.f};
  acc0 = __builtin_amdgcn_mfma_f32_16x16x32_bf16(a0, b00, acc0, 0,0,0);
  acc0 = __builtin_amdgcn_mfma_f32_16x16x32_bf16(a1, b01, acc0, 0,0,0);
  acc1 = __builtin_amdgcn_mfma_f32_16x16x32_bf16(a0, b10, acc1, 0,0,0);
  acc1 = __builtin_amdgcn_mfma_f32_16x16x32_bf16(a1, b11, acc1, 0,0,0);

  float wlo = ww1[lr], whi = ww1[16 + lr];
  float bias = wb1[0];
  float s[4];
  #pragma unroll
  for (int r=0;r<4;r++){
    int pe_er = __shfl((int)pe, lg*4 + r);     // edge lg*4+r metadata
    int rel = ((unsigned)pe_er) >> 17;
    float v0 = fmaxf(acc0[r] + hrW1[rel*ATTN + lr],      0.f);
    float v1 = fmaxf(acc1[r] + hrW1[rel*ATTN + 16 + lr], 0.f);
    float p = fmaf(v0, wlo, v1*whi);
    p += __shfl_xor(p, 1);
    p += __shfl_xor(p, 2);
    p += __shfl_xor(p, 4);
    p += __shfl_xor(p, 8);
    s[r] = sigf(p + bias);                     // all lanes: alpha of edge lg*4+r
  }

  // ---- phase 2: segmented accumulate, lane l = channel l ----
  const int nodeBase = bkt * CBN;
  float acc = 0.f;
  int prev = -1;
  #pragma unroll
  for (int e=0; e<16; ++e){
    int pe_e = __shfl((int)pe, e);
    int ns_e = __shfl(ns, e);
    float al = __shfl(s[e & 3], (e >> 2) * 16);
    if (e < nv){
      int sub_e = pe_e & 0x1FFFF;
      int rel_e = ((unsigned)pe_e) >> 17;
      float hv = bf2f(h16[(size_t)sub_e*HID + l]);   // L1-hot (phase 1)
      float rv = bf2f(re16[rel_e*HID + l]);
      if (ns_e != prev){
        if (prev >= 0)
          atomicAdd(&agg32[(size_t)(nodeBase + prev)*HID + l], acc);
        acc = 0.f;
        prev = ns_e;
      }
      acc = fmaf(al, hv + rv, acc);
    }
  }
  if (prev >= 0)
    atomicAdd(&agg32[(size_t)(nodeBase + prev)*HID + l], acc);
}

// ---- MFMA node phase: 64 nodes/block, wave w owns nodes w*16..w*16+15 ----
template<int HAS_H0, int AGGF32>
__global__ void __launch_bounds__(256, 2) k_node2(
    const void* __restrict__ aggP,
    const unsigned short* __restrict__ h16,
    const unsigned short* __restrict__ pkWh,
    const unsigned short* __restrict__ pkWih,
    const unsigned short* __restrict__ pkWhh,
    const float* __restrict__ bih, const float* __restrict__ bhh,
    unsigned short* __restrict__ h16_out,
    const float* __restrict__ wf, float* __restrict__ score, int mode)
{
  __shared__ unsigned short xlds[4096];   // 4 waves x [16 rows][64 cols] bf16, swizzled

  const int t  = threadIdx.x;
  const int w  = t >> 6, l = t & 63;
  const int lr = l & 15;                  // fragment row/col
  const int lg = l >> 4;                  // k-group
  const int n0 = blockIdx.x * 64;
  const int rowA = n0 + w*16 + lr;

  bf16x8 aA0, aA1;
  if (AGGF32){
    const float4* ap = (const float4*)((const float*)aggP + (size_t)rowA*HID);
    float4 u0 = ap[lg*2], u1 = ap[lg*2+1];
    float4 u2 = ap[8+lg*2], u3 = ap[9+lg*2];
    aA0 = pk8(u0, u1); aA1 = pk8(u2, u3);
  } else {
    const unsigned short* a16 = (const unsigned short*)aggP;
    aA0 = *(const bf16x8*)(a16 + (size_t)rowA*HID + lg*8);
    aA1 = *(const bf16x8*)(a16 + (size_t)rowA*HID + 32 + lg*8);
  }
  bf16x8 hA0, hA1;
  if (HAS_H0){
    hA0 = *(const bf16x8*)(h16 + (size_t)rowA*HID + lg*8);
    hA1 = *(const bf16x8*)(h16 + (size_t)rowA*HID + 32 + lg*8);
  }

  float bir[4],biz[4],bin[4],bhr[4],bhz[4],bhn[4],wfv[4];
  #pragma unroll
  for (int nt=0;nt<4;nt++){
    int ch = nt*16 + lr;
    bir[nt]=bih[ch]; biz[nt]=bih[64+ch]; bin[nt]=bih[128+ch];
    bhr[nt]=bhh[ch]; bhz[nt]=bhh[64+ch]; bhn[nt]=bhh[128+ch];
    wfv[nt]=wf[ch];
  }

  // ---- X = relu(agg @ Wh^T) ----
  #pragma unroll
  for (int nt=0;nt<4;nt++){
    f32x4 acc = {0.f,0.f,0.f,0.f};
    bf16x8 b0 = *(const bf16x8*)(pkWh + (size_t)((nt*2+0)*64 + l)*8);
    bf16x8 b1 = *(const bf16x8*)(pkWh + (size_t)((nt*2+1)*64 + l)*8);
    acc = __builtin_amdgcn_mfma_f32_16x16x32_bf16(aA0, b0, acc, 0,0,0);
    acc = __builtin_amdgcn_mfma_f32_16x16x32_bf16(aA1, b1, acc, 0,0,0);
    #pragma unroll
    for (int r=0;r<4;r++){
      int m = lg*4 + r, col = nt*16 + lr;
      xlds[w*1024 + m*64 + (col ^ ((m&7)<<3))] = f2bf(fmaxf(acc[r], 0.f));
    }
  }
  __syncthreads();

  const int xbase = w*1024 + lr*64;
  const int sw = (lr&7)<<3;
  bf16x8 xA0 = *(const bf16x8*)&xlds[xbase + ((lg*8)      ^ sw)];
  bf16x8 xA1 = *(const bf16x8*)&xlds[xbase + ((32 + lg*8) ^ sw)];

  // ---- gate passes ----
  float rv[16], zv[16], hv[16];
  #pragma unroll
  for (int g=0; g<2; ++g){               // g=0: r-gate, g=1: z-gate
    #pragma unroll
    for (int nt=0;nt<4;nt++){
      int gt = g*4 + nt;
      f32x4 ai = {0.f,0.f,0.f,0.f};
      bf16x8 bi0 = *(const bf16x8*)(pkWih + (size_t)((gt*2+0)*64 + l)*8);
      bf16x8 bi1 = *(const bf16x8*)(pkWih + (size_t)((gt*2+1)*64 + l)*8);
      ai = __builtin_amdgcn_mfma_f32_16x16x32_bf16(xA0, bi0, ai, 0,0,0);
      ai = __builtin_amdgcn_mfma_f32_16x16x32_bf16(xA1, bi1, ai, 0,0,0);
      f32x4 ah = {0.f,0.f,0.f,0.f};
      if (HAS_H0){
        bf16x8 bh0 = *(const bf16x8*)(pkWhh + (size_t)((gt*2+0)*64 + l)*8);
        bf16x8 bh1 = *(const bf16x8*)(pkWhh + (size_t)((gt*2+1)*64 + l)*8);
        ah = __builtin_amdgcn_mfma_f32_16x16x32_bf16(hA0, bh0, ah, 0,0,0);
        ah = __builtin_amdgcn_mfma_f32_16x16x32_bf16(hA1, bh1, ah, 0,0,0);
      }
      #pragma unroll
      for (int r=0;r<4;r++){
        float bi_ = (g==0) ? bir[nt] : biz[nt];
        float bh_ = (g==0) ? bhr[nt] : bhz[nt];
        float v = sigf(ai[r] + bi_ + ah[r] + bh_);
        if (g==0) rv[nt*4+r] = v; else zv[nt*4+r] = v;
      }
    }
  }
  #pragma unroll
  for (int nt=0;nt<4;nt++){              // n-gate + GRU blend
    int gt = 8 + nt;
    f32x4 ai = {0.f,0.f,0.f,0.f};
    bf16x8 bi0 = *(const bf16x8*)(pkWih + (size_t)((gt*2+0)*64 + l)*8);
    bf16x8 bi1 = *(const bf16x8*)(pkWih + (size_t)((gt*2+1)*64 + l)*8);
    ai = __builtin_amdgcn_mfma_f32_16x16x32_bf16(xA0, bi0, ai, 0,0,0);
    ai = __builtin_amdgcn_mfma_f32_16x16x32_bf16(xA1, bi1, ai, 0,0,0);
    f32x4 ah = {0.f,0.f,0.f,0.f};
    if (HAS_H0){
      bf16x8 bh0 = *(const bf16x8*)(pkWhh + (size_t)((gt*2+0)*64 + l)*8);
      bf16x8 bh1 = *(const bf16x8*)(pkWhh + (size_t)((gt*2+1)*64 + l)*8);
      ah = __builtin_amdgcn_mfma_f32_16x16x32_bf16(hA0, bh0, ah, 0,0,0);
      ah = __builtin_amdgcn_mfma_f32_16x16x32_bf16(hA1, bh1, ah, 0,0,0);
    }
    #pragma unroll
    for (int r=0;r<4;r++){
      float gin = ai[r] + bin[nt];
      float ghn = ah[r] + bhn[nt];
      float rr  = rv[nt*4+r];
      float nn  = tanhf(fmaf(rr, ghn, gin));
      float z   = zv[nt*4+r];
      float h0v = 0.f;
      if (HAS_H0)
        h0v = bf2f(h16[(size_t)(n0 + w*16 + lg*4 + r)*HID + nt*16 + lr]);
      hv[nt*4+r] = (1.f - z)*nn + z*h0v;
    }
  }

  if (mode == 0){
    __syncthreads();
    #pragma unroll
    for (int nt=0;nt<4;nt++)
      #pragma unroll
      for (int r=0;r<4;r++){
        int m = lg*4 + r, col = nt*16 + lr;
        xlds[w*1024 + m*64 + (col ^ ((m&7)<<3))] = f2bf(hv[nt*4+r]);
      }
    __syncthreads();
    int rr2 = l >> 2, cc = l & 3;
    int n = n0 + w*16 + rr2;
    if (n < N_NODE){
      int base = w*1024 + rr2*64, s2 = (rr2&7)<<3;
      bf16x8 v0 = *(const bf16x8*)&xlds[base + ((cc*16)     ^ s2)];
      bf16x8 v1 = *(const bf16x8*)&xlds[base + ((cc*16 + 8) ^ s2)];
      *(bf16x8*)(h16_out + (size_t)n*HID + cc*16)     = v0;
      *(bf16x8*)(h16_out + (size_t)n*HID + cc*16 + 8) = v1;
    }
  } else {
    #pragma unroll
    for (int r=0;r<4;r++){
      float p = 0.f;
      #pragma unroll
      for (int nt=0;nt<4;nt++) p = fmaf(hv[nt*4+r], wfv[nt], p);
      p += __shfl_xor(p, 1);
      p += __shfl_xor(p, 2);
      p += __shfl_xor(p, 4);
      p += __shfl_xor(p, 8);
      if (lr == 0){
        int n = n0 + w*16 + lg*4 + r;
        if (n < N_NODE) score[n] = p;
      }
    }
  }
}

extern "C" void kernel_launch(void* const* d_in, const int* in_sizes, int n_in,
                              void* d_out, int out_size, void* d_ws, size_t ws_size,
                              hipStream_t stream)
{
  const int*   edges = (const int*)  d_in[0];
  const float* re    = (const float*)d_in[1];
  const float* Ws    = (const float*)d_in[2];
  const float* Wr    = (const float*)d_in[3];
  const float* ww    = (const float*)d_in[4];
  const float* wb    = (const float*)d_in[5];
  const float* Wh    = (const float*)d_in[6];
  const float* Wih   = (const float*)d_in[7];
  const float* Whh   = (const float*)d_in[8];
  const float* bih   = (const float*)d_in[9];
  const float* bhh   = (const float*)d_in[10];
  const float* wf    = (const float*)d_in[11];
  float* out = (float*)d_out;

  // workspace layout
  unsigned short* agg16  = (unsigned short*)d_ws;              // N_PAD*HID
  unsigned short* h16    = agg16 + (size_t)N_PAD*HID;          // N_PAD*HID
  unsigned short* srel16 = h16 + (size_t)N_PAD*HID;            // REL_VOCAB*HID
  unsigned short* re16   = srel16 + REL_VOCAB*HID;             // REL_VOCAB*HID
  unsigned short* pkWh   = re16 + REL_VOCAB*HID;               // 2*4096
  unsigned short* pkWih  = pkWh  + 2*4096;                     // 2*12288
  unsigned short* pkWhh  = pkWih + 2*12288;                    // 2*12288
  unsigned short* pkWs   = pkWhh + 2*12288;                    // 2048
  float* hrW1      = (float*)(pkWs + 2048);                    // REL_VOCAB*ATTN
  float* agg32     = hrW1 + REL_VOCAB*ATTN;                    // N_PAD*HID f32
  uint2* tmp       = (uint2*)(agg32 + (size_t)N_PAD*HID);      // N_SLOT uint2
  unsigned int* pairP = (unsigned int*)(tmp + N_SLOT);         // N_SLOT uint
  unsigned short* nodeS = (unsigned short*)(pairP + N_SLOT);   // N_SLOT u16
  int*   startArr  = (int*)(nodeS + N_SLOT);                   // NCB*CBN
  int*   endArr    = startArr + NCB*CBN;                       // NCB*CBN
  int*   gcursor   = endArr + NCB*CBN;                         // 256 (pad)

  // ---- zero cursors + fp32 agg ----
  k_izero<<<1, 256, 0, stream>>>(gcursor, 256);
  k_zero4<<<((N_PAD*HID/4) + 255)/256, 256, 0, stream>>>((float4*)agg32, N_PAD*HID/4);

  // ---- two-pass bucket sort of edges by obj ----
  k_part<<<(N_EDGE + ACHUNK - 1)/ACHUNK, 256, 0, stream>>>(edges, gcursor, tmp);
  k_bsort2<<<NCB, 256, 0, stream>>>(tmp, gcursor, pairP, nodeS, startArr, endArr);

  // ---- per-relation tables + packed bf16 weights ----
  k_pre<<<(REL_VOCAB*64+255)/256, 256, 0, stream>>>(re, Wr, ww, wb, srel16, re16, hrW1);
  k_wt<<<(116*64+255)/256, 256, 0, stream>>>(Wh, Wih, Whh, Ws, pkWh, pkWih, pkWhh, pkWs);

  const int NB_NODE2 = (N_NODE + 63) / 64;

  // ---- layer 0 ----
  k_agg0<<<(N_NODE*64)/256, 256, 0, stream>>>(startArr, endArr, pairP, srel16, agg16);
  k_node2<0,0><<<NB_NODE2, 256, 0, stream>>>(agg16, h16,
        pkWh, pkWih, pkWhh, bih, bhh, h16, wf, out, 0);

  // ---- layer 1 (fused alpha + aggregate) ----
  k_fuse1<<<N_SLOT/64, 256, 0, stream>>>(pairP, nodeS, gcursor, h16, hrW1, pkWs,
        ww + ATTN, wb + 1, re16, agg32);
  k_node2<1,1><<<NB_NODE2, 256, 0, stream>>>(agg32, h16,
        pkWh + 4096, pkWih + 12288, pkWhh + 12288, bih + 3*HID, bhh + 3*HID,
        h16, wf, out, 1);
}

// Round 13
// 202.528 us; speedup vs baseline: 1.0842x; 1.0842x over previous
//
#include <hip/hip_runtime.h>

#define N_NODE 100000
#define N_PAD  100064            // padded rows for OOB-safe fragment loads
#define N_EDGE 1000000
#define HID 64
#define ATTN 32
#define REL_VOCAB 2005

#define CBSHIFT 9
#define CBN    512               // nodes per coarse bucket
#define NCB    196               // ceil(N_NODE/CBN)
#define MAXCB  8192              // slots per bucket region (mean 5120, +43σ)
#define LCAP   6400              // LDS sort capacity (mean +18σ)
#define N_SLOT (NCB*MAXCB)       // 1,605,632 padded slots
#define ACHUNK 4096              // edges per k_part block

typedef short  bf16x8 __attribute__((ext_vector_type(8)));
typedef float  f32x4  __attribute__((ext_vector_type(4)));

__device__ __forceinline__ float sigf(float x){ return 1.0f/(1.0f+__expf(-x)); }
__device__ __forceinline__ float bf2f(unsigned short u){
  return __uint_as_float(((unsigned int)u) << 16);
}
__device__ __forceinline__ unsigned short f2bf(float f){  // RNE
  unsigned int x = __float_as_uint(f);
  x += 0x7fffu + ((x >> 16) & 1u);
  return (unsigned short)(x >> 16);
}

__device__ __forceinline__ float dot64(const float4* a, const float4* __restrict__ w){
  float s0=0.f,s1=0.f,s2=0.f,s3=0.f;
  #pragma unroll
  for (int i=0;i<16;i++){
    float4 av=a[i]; float4 wv=w[i];
    s0=fmaf(av.x,wv.x,s0); s1=fmaf(av.y,wv.y,s1);
    s2=fmaf(av.z,wv.z,s2); s3=fmaf(av.w,wv.w,s3);
  }
  return (s0+s1)+(s2+s3);
}

// ---- per-relation precompute, wave-parallel: one wave per relation ----
__global__ void __launch_bounds__(256, 4) k_pre(
    const float* __restrict__ re, const float* __restrict__ Wr,
    const float* __restrict__ ww, const float* __restrict__ wb,
    unsigned short* __restrict__ srel16, unsigned short* __restrict__ re16,
    float* __restrict__ hrW1)
{
  int w = (blockIdx.x*blockDim.x + threadIdx.x) >> 6;
  int l = threadIdx.x & 63;
  if (w >= REL_VOCAB) return;
  const int r = w;
  const int j = l & 31;
  const bool hi = (l >= 32);

  float4 ev[16];
  const float4* ep = (const float4*)(re + (size_t)(hi ? REL_VOCAB + r : r)*HID);
  #pragma unroll
  for (int i=0;i<16;i++) ev[i]=ep[i];

  const float4* wrow = (const float4*)(Wr + (size_t)(hi ? ATTN + j : j)*HID);
  float d = dot64(ev, wrow);

  if (hi) hrW1[r*ATTN + j] = d;

  float p = hi ? 0.f : fmaxf(d, 0.f) * ww[j];
  p += __shfl_xor(p, 1);
  p += __shfl_xor(p, 2);
  p += __shfl_xor(p, 4);
  p += __shfl_xor(p, 8);
  p += __shfl_xor(p, 16);
  p += __shfl_xor(p, 32);
  float alpha = sigf(p + wb[0]);

  float e0l = re[(size_t)r*HID + l];
  float e1l = re[(size_t)(REL_VOCAB + r)*HID + l];
  srel16[r*HID + l] = f2bf(alpha * e0l);
  re16[r*HID + l]   = f2bf(e1l);
}

__global__ void k_izero(int* __restrict__ p, int n){
  int i = blockIdx.x*blockDim.x + threadIdx.x;
  if (i < n) p[i] = 0;
}

// ---- weight pack into bf16 MFMA B-fragment order ----
__global__ void k_wt(const float* __restrict__ Wh, const float* __restrict__ Wih,
                     const float* __restrict__ Whh, const float* __restrict__ Ws,
                     unsigned short* __restrict__ pkWh, unsigned short* __restrict__ pkWih,
                     unsigned short* __restrict__ pkWhh, unsigned short* __restrict__ pkWs)
{
  int tid = blockIdx.x*blockDim.x + threadIdx.x;
  if (tid >= 116*64) return;
  int rec = tid >> 6, l = tid & 63;
  const float* src; unsigned short* dst; int tile, c;
  if (rec < 16){
    int li = rec >> 3, q = rec & 7; tile = q >> 1; c = q & 1;
    src = Wh + li*4096;
    dst = pkWh + (size_t)((li*8 + q)*64 + l)*8;
  } else if (rec < 64){
    int q2 = rec - 16; int li = q2 / 24, q = q2 % 24; tile = q >> 1; c = q & 1;
    src = Wih + li*12288;
    dst = pkWih + (size_t)((li*24 + q)*64 + l)*8;
  } else if (rec < 112){
    int q2 = rec - 64; int li = q2 / 24, q = q2 % 24; tile = q >> 1; c = q & 1;
    src = Whh + li*12288;
    dst = pkWhh + (size_t)((li*24 + q)*64 + l)*8;
  } else {
    int q = rec - 112; tile = q >> 1; c = q & 1;
    src = Ws + ATTN*HID;                       // layer-1 Ws only
    dst = pkWs + (size_t)(q*64 + l)*8;
  }
  int row = tile*16 + (l&15);
  int k0  = c*32 + (l>>4)*8;
  #pragma unroll
  for (int j=0;j<8;j++) dst[j] = f2bf(src[row*64 + k0 + j]);
}

// ---- pass A: block-level partition into 196 coarse buckets ----
__global__ void __launch_bounds__(256, 4) k_part(
    const int* __restrict__ edges, int* __restrict__ gcursor,
    uint2* __restrict__ tmp)
{
  __shared__ int hcnt[NCB];
  __shared__ int hbase[NCB];
  __shared__ int hcur[NCB];
  const int t = threadIdx.x;
  const int base = blockIdx.x * ACHUNK;
  const int nE = min(ACHUNK, N_EDGE - base);

  if (t < NCB){ hcnt[t] = 0; }
  __syncthreads();

  unsigned pk[16]; int bb[16], lo[16];
  const int2* e2 = (const int2*)edges;
  #pragma unroll
  for (int j=0;j<16;j++){
    int idx = j*256 + t;
    if (idx < nE){
      int e = base + idx;
      int rel = e2[e*3+1].x;
      int2 so = e2[e*3+2];
      pk[j] = ((unsigned)rel << 17) | (unsigned)so.x;
      bb[j] = so.y >> CBSHIFT;
      lo[j] = so.y & (CBN-1);
      atomicAdd(&hcnt[bb[j]], 1);
    } else bb[j] = -1;
  }
  __syncthreads();
  if (t < NCB){
    hbase[t] = (hcnt[t] > 0) ? atomicAdd(&gcursor[t], hcnt[t]) : 0;
    hcur[t] = 0;
  }
  __syncthreads();
  #pragma unroll
  for (int j=0;j<16;j++){
    if (bb[j] >= 0){
      int pos = hbase[bb[j]] + atomicAdd(&hcur[bb[j]], 1);
      if (pos < MAXCB)
        tmp[(size_t)bb[j]*MAXCB + pos] = make_uint2(pk[j], (unsigned)lo[j]);
    }
  }
}

// ---- pass B: in-bucket counting sort, one block per coarse bucket ----
__global__ void __launch_bounds__(256, 2) k_bsort2(
    const uint2* __restrict__ tmp, const int* __restrict__ gcursor,
    unsigned int* __restrict__ pairP, int* __restrict__ startArr,
    int* __restrict__ endArr)
{
  __shared__ int lcnt[CBN];
  __shared__ int lsc[CBN];
  __shared__ int lcur[CBN];
  __shared__ unsigned int lout[LCAP];
  const int b = blockIdx.x, t = threadIdx.x;
  const int base = b*MAXCB;
  const int size = min(gcursor[b], LCAP);

  lcnt[t] = 0; lcnt[256+t] = 0;
  __syncthreads();
  for (int i=t; i<size; i+=256)
    atomicAdd(&lcnt[tmp[base+i].y], 1);
  __syncthreads();

  int cA = lcnt[t], cB = lcnt[256+t];
  lsc[t] = cA; lsc[256+t] = cB;
  __syncthreads();
  #pragma unroll
  for (int off=1; off<256; off<<=1){
    int vA = (t>=off) ? lsc[t-off] : 0;
    int vB = (t>=off) ? lsc[256+t-off] : 0;
    __syncthreads();
    lsc[t] += vA; lsc[256+t] += vB;
    __syncthreads();
  }
  int totA = lsc[255];
  __syncthreads();
  lsc[256+t] += totA;
  __syncthreads();

  {
    int inclA = lsc[t], exclA = inclA - cA;
    lcur[t] = exclA;
    int n = b*CBN + t;
    if (n < N_NODE){ startArr[n] = base + exclA; endArr[n] = base + inclA; }
    int inclB = lsc[256+t], exclB = inclB - cB;
    lcur[256+t] = exclB;
    int n2 = b*CBN + 256 + t;
    if (n2 < N_NODE){ startArr[n2] = base + exclB; endArr[n2] = base + inclB; }
  }
  __syncthreads();

  for (int i=t; i<size; i+=256){
    uint2 p = tmp[base+i];
    int pos = atomicAdd(&lcur[p.y], 1);
    lout[pos] = p.x;
  }
  __syncthreads();
  for (int i=t; i<size; i+=256)
    pairP[base+i] = lout[i];
}

// ---- layer-0 aggregation: wave per node (bf16 table) -> bf16 agg ----
__global__ void k_agg0(const int* __restrict__ startArr, const int* __restrict__ endArr,
                       const unsigned int* __restrict__ pairP,
                       const unsigned short* __restrict__ srel16,
                       unsigned short* __restrict__ agg16)
{
  int t = blockIdx.x*blockDim.x + threadIdx.x;
  int n = __builtin_amdgcn_readfirstlane(t >> 6);
  int k = t & 63;
  if (n >= N_NODE) return;
  int b = startArr[n], e_ = endArr[n];
  float acc = 0.f;
  int i = b;
  for (; i+3 < e_; i += 4){
    int r0=pairP[i]>>17, r1=pairP[i+1]>>17, r2=pairP[i+2]>>17, r3=pairP[i+3]>>17;
    float v0=bf2f(srel16[r0*HID+k]), v1=bf2f(srel16[r1*HID+k]);
    float v2=bf2f(srel16[r2*HID+k]), v3=bf2f(srel16[r3*HID+k]);
    acc += v0; acc += v1; acc += v2; acc += v3;
  }
  for (; i < e_; ++i) acc += bf2f(srel16[(pairP[i]>>17)*HID + k]);
  agg16[(size_t)n*HID + k] = f2bf(acc);
}

// ---- fused layer-1 edge phase, wave per NODE ----
// per 16-edge chunk: alpha via 4x mfma_16x16x32 (h16 rows as A-frags, lane
// lr = edge), then a channel-parallel walk over the chunk's edges (lane l =
// channel l) reusing the L1-hot rows. Single owner per node: no atomics, no
// segment logic; one bf16 row store at the end.
__global__ void __launch_bounds__(256, 4) k_fuse2(
    const int* __restrict__ startArr, const int* __restrict__ endArr,
    const unsigned int* __restrict__ pairP,
    const unsigned short* __restrict__ h16,
    const float* __restrict__ hrW1, const unsigned short* __restrict__ pkWs,
    const float* __restrict__ ww1, const float* __restrict__ wb1,
    const unsigned short* __restrict__ re16,
    unsigned short* __restrict__ agg16)
{
  const int t = threadIdx.x;
  const int w = t >> 6, l = t & 63;
  const int lr = l & 15, lg = l >> 4;
  const int n = __builtin_amdgcn_readfirstlane(blockIdx.x*4 + w);
  if (n >= N_NODE) return;
  const int b = startArr[n], e_ = endArr[n];

  // chunk-invariant operands (L1-resident)
  bf16x8 b00 = *(const bf16x8*)(pkWs + (size_t)(0*64 + l)*8);
  bf16x8 b01 = *(const bf16x8*)(pkWs + (size_t)(1*64 + l)*8);
  bf16x8 b10 = *(const bf16x8*)(pkWs + (size_t)(2*64 + l)*8);
  bf16x8 b11 = *(const bf16x8*)(pkWs + (size_t)(3*64 + l)*8);
  const float wlo = ww1[lr], whi = ww1[16 + lr];
  const float bias = wb1[0];

  float acc = 0.f;
  for (int c = b; c < e_; c += 16){
    const int nv = e_ - c;                       // wave-uniform; >=1

    // edge lr of this chunk (reads past e_ are masked; memory in-workspace)
    unsigned pe = pairP[c + lr];
    int subA = (int)(pe & 0x1FFFFu);
    bf16x8 a0 = *(const bf16x8*)(h16 + (size_t)subA*HID + lg*8);
    bf16x8 a1 = *(const bf16x8*)(h16 + (size_t)subA*HID + 32 + lg*8);

    f32x4 acc0 = {0.f,0.f,0.f,0.f}, acc1 = {0.f,0.f,0.f,0.f};
    acc0 = __builtin_amdgcn_mfma_f32_16x16x32_bf16(a0, b00, acc0, 0,0,0);
    acc0 = __builtin_amdgcn_mfma_f32_16x16x32_bf16(a1, b01, acc0, 0,0,0);
    acc1 = __builtin_amdgcn_mfma_f32_16x16x32_bf16(a0, b10, acc1, 0,0,0);
    acc1 = __builtin_amdgcn_mfma_f32_16x16x32_bf16(a1, b11, acc1, 0,0,0);

    // alpha epilogue: after reduce, all 16 lanes of group lg hold alpha of
    // edge c + lg*4 + r in s[r]
    float s[4];
    #pragma unroll
    for (int r=0;r<4;r++){
      int pe_er = __shfl((int)pe, lg*4 + r);
      int rel = ((unsigned)pe_er) >> 17;
      float v0 = fmaxf(acc0[r] + hrW1[rel*ATTN + lr],      0.f);
      float v1 = fmaxf(acc1[r] + hrW1[rel*ATTN + 16 + lr], 0.f);
      float p = fmaf(v0, wlo, v1*whi);
      p += __shfl_xor(p, 1);
      p += __shfl_xor(p, 2);
      p += __shfl_xor(p, 4);
      p += __shfl_xor(p, 8);
      s[r] = sigf(p + bias);
    }

    // channel-parallel walk over this chunk's edges (rows L1-hot)
    #pragma unroll
    for (int e=0; e<16; ++e){
      if (e >= nv) break;                        // wave-uniform branch
      int pe_e = __shfl((int)pe, e);
      float al = __shfl(s[e & 3], (e >> 2) * 16);
      int sub_e = pe_e & 0x1FFFF;
      int rel_e = ((unsigned)pe_e) >> 17;
      float hv = bf2f(h16[(size_t)sub_e*HID + l]);
      float rv = bf2f(re16[rel_e*HID + l]);
      acc = fmaf(al, hv + rv, acc);
    }
  }
  agg16[(size_t)n*HID + l] = f2bf(acc);
}

// ---- MFMA node phase: 64 nodes/block, wave w owns nodes w*16..w*16+15 ----
template<int HAS_H0>
__global__ void __launch_bounds__(256, 2) k_node2(
    const unsigned short* __restrict__ agg16,
    const unsigned short* __restrict__ h16,
    const unsigned short* __restrict__ pkWh,
    const unsigned short* __restrict__ pkWih,
    const unsigned short* __restrict__ pkWhh,
    const float* __restrict__ bih, const float* __restrict__ bhh,
    unsigned short* __restrict__ h16_out,
    const float* __restrict__ wf, float* __restrict__ score, int mode)
{
  __shared__ unsigned short xlds[4096];   // 4 waves x [16 rows][64 cols] bf16, swizzled

  const int t  = threadIdx.x;
  const int w  = t >> 6, l = t & 63;
  const int lr = l & 15;                  // fragment row/col
  const int lg = l >> 4;                  // k-group
  const int n0 = blockIdx.x * 64;
  const int rowA = n0 + w*16 + lr;

  bf16x8 aA0 = *(const bf16x8*)(agg16 + (size_t)rowA*HID + lg*8);
  bf16x8 aA1 = *(const bf16x8*)(agg16 + (size_t)rowA*HID + 32 + lg*8);
  bf16x8 hA0, hA1;
  if (HAS_H0){
    hA0 = *(const bf16x8*)(h16 + (size_t)rowA*HID + lg*8);
    hA1 = *(const bf16x8*)(h16 + (size_t)rowA*HID + 32 + lg*8);
  }

  float bir[4],biz[4],bin[4],bhr[4],bhz[4],bhn[4],wfv[4];
  #pragma unroll
  for (int nt=0;nt<4;nt++){
    int ch = nt*16 + lr;
    bir[nt]=bih[ch]; biz[nt]=bih[64+ch]; bin[nt]=bih[128+ch];
    bhr[nt]=bhh[ch]; bhz[nt]=bhh[64+ch]; bhn[nt]=bhh[128+ch];
    wfv[nt]=wf[ch];
  }

  // ---- X = relu(agg @ Wh^T) ----
  #pragma unroll
  for (int nt=0;nt<4;nt++){
    f32x4 acc = {0.f,0.f,0.f,0.f};
    bf16x8 b0 = *(const bf16x8*)(pkWh + (size_t)((nt*2+0)*64 + l)*8);
    bf16x8 b1 = *(const bf16x8*)(pkWh + (size_t)((nt*2+1)*64 + l)*8);
    acc = __builtin_amdgcn_mfma_f32_16x16x32_bf16(aA0, b0, acc, 0,0,0);
    acc = __builtin_amdgcn_mfma_f32_16x16x32_bf16(aA1, b1, acc, 0,0,0);
    #pragma unroll
    for (int r=0;r<4;r++){
      int m = lg*4 + r, col = nt*16 + lr;
      xlds[w*1024 + m*64 + (col ^ ((m&7)<<3))] = f2bf(fmaxf(acc[r], 0.f));
    }
  }
  __syncthreads();

  const int xbase = w*1024 + lr*64;
  const int sw = (lr&7)<<3;
  bf16x8 xA0 = *(const bf16x8*)&xlds[xbase + ((lg*8)      ^ sw)];
  bf16x8 xA1 = *(const bf16x8*)&xlds[xbase + ((32 + lg*8) ^ sw)];

  // ---- gate passes ----
  float rv[16], zv[16], hv[16];
  #pragma unroll
  for (int g=0; g<2; ++g){               // g=0: r-gate, g=1: z-gate
    #pragma unroll
    for (int nt=0;nt<4;nt++){
      int gt = g*4 + nt;
      f32x4 ai = {0.f,0.f,0.f,0.f};
      bf16x8 bi0 = *(const bf16x8*)(pkWih + (size_t)((gt*2+0)*64 + l)*8);
      bf16x8 bi1 = *(const bf16x8*)(pkWih + (size_t)((gt*2+1)*64 + l)*8);
      ai = __builtin_amdgcn_mfma_f32_16x16x32_bf16(xA0, bi0, ai, 0,0,0);
      ai = __builtin_amdgcn_mfma_f32_16x16x32_bf16(xA1, bi1, ai, 0,0,0);
      f32x4 ah = {0.f,0.f,0.f,0.f};
      if (HAS_H0){
        bf16x8 bh0 = *(const bf16x8*)(pkWhh + (size_t)((gt*2+0)*64 + l)*8);
        bf16x8 bh1 = *(const bf16x8*)(pkWhh + (size_t)((gt*2+1)*64 + l)*8);
        ah = __builtin_amdgcn_mfma_f32_16x16x32_bf16(hA0, bh0, ah, 0,0,0);
        ah = __builtin_amdgcn_mfma_f32_16x16x32_bf16(hA1, bh1, ah, 0,0,0);
      }
      #pragma unroll
      for (int r=0;r<4;r++){
        float bi_ = (g==0) ? bir[nt] : biz[nt];
        float bh_ = (g==0) ? bhr[nt] : bhz[nt];
        float v = sigf(ai[r] + bi_ + ah[r] + bh_);
        if (g==0) rv[nt*4+r] = v; else zv[nt*4+r] = v;
      }
    }
  }
  #pragma unroll
  for (int nt=0;nt<4;nt++){              // n-gate + GRU blend
    int gt = 8 + nt;
    f32x4 ai = {0.f,0.f,0.f,0.f};
    bf16x8 bi0 = *(const bf16x8*)(pkWih + (size_t)((gt*2+0)*64 + l)*8);
    bf16x8 bi1 = *(const bf16x8*)(pkWih + (size_t)((gt*2+1)*64 + l)*8);
    ai = __builtin_amdgcn_mfma_f32_16x16x32_bf16(xA0, bi0, ai, 0,0,0);
    ai = __builtin_amdgcn_mfma_f32_16x16x32_bf16(xA1, bi1, ai, 0,0,0);
    f32x4 ah = {0.f,0.f,0.f,0.f};
    if (HAS_H0){
      bf16x8 bh0 = *(const bf16x8*)(pkWhh + (size_t)((gt*2+0)*64 + l)*8);
      bf16x8 bh1 = *(const bf16x8*)(pkWhh + (size_t)((gt*2+1)*64 + l)*8);
      ah = __builtin_amdgcn_mfma_f32_16x16x32_bf16(hA0, bh0, ah, 0,0,0);
      ah = __builtin_amdgcn_mfma_f32_16x16x32_bf16(hA1, bh1, ah, 0,0,0);
    }
    #pragma unroll
    for (int r=0;r<4;r++){
      float gin = ai[r] + bin[nt];
      float ghn = ah[r] + bhn[nt];
      float rr  = rv[nt*4+r];
      float nn  = tanhf(fmaf(rr, ghn, gin));
      float z   = zv[nt*4+r];
      float h0v = 0.f;
      if (HAS_H0)
        h0v = bf2f(h16[(size_t)(n0 + w*16 + lg*4 + r)*HID + nt*16 + lr]);
      hv[nt*4+r] = (1.f - z)*nn + z*h0v;
    }
  }

  if (mode == 0){
    __syncthreads();
    #pragma unroll
    for (int nt=0;nt<4;nt++)
      #pragma unroll
      for (int r=0;r<4;r++){
        int m = lg*4 + r, col = nt*16 + lr;
        xlds[w*1024 + m*64 + (col ^ ((m&7)<<3))] = f2bf(hv[nt*4+r]);
      }
    __syncthreads();
    int rr2 = l >> 2, cc = l & 3;
    int n = n0 + w*16 + rr2;
    if (n < N_NODE){
      int base = w*1024 + rr2*64, s2 = (rr2&7)<<3;
      bf16x8 v0 = *(const bf16x8*)&xlds[base + ((cc*16)     ^ s2)];
      bf16x8 v1 = *(const bf16x8*)&xlds[base + ((cc*16 + 8) ^ s2)];
      *(bf16x8*)(h16_out + (size_t)n*HID + cc*16)     = v0;
      *(bf16x8*)(h16_out + (size_t)n*HID + cc*16 + 8) = v1;
    }
  } else {
    #pragma unroll
    for (int r=0;r<4;r++){
      float p = 0.f;
      #pragma unroll
      for (int nt=0;nt<4;nt++) p = fmaf(hv[nt*4+r], wfv[nt], p);
      p += __shfl_xor(p, 1);
      p += __shfl_xor(p, 2);
      p += __shfl_xor(p, 4);
      p += __shfl_xor(p, 8);
      if (lr == 0){
        int n = n0 + w*16 + lg*4 + r;
        if (n < N_NODE) score[n] = p;
      }
    }
  }
}

extern "C" void kernel_launch(void* const* d_in, const int* in_sizes, int n_in,
                              void* d_out, int out_size, void* d_ws, size_t ws_size,
                              hipStream_t stream)
{
  const int*   edges = (const int*)  d_in[0];
  const float* re    = (const float*)d_in[1];
  const float* Ws    = (const float*)d_in[2];
  const float* Wr    = (const float*)d_in[3];
  const float* ww    = (const float*)d_in[4];
  const float* wb    = (const float*)d_in[5];
  const float* Wh    = (const float*)d_in[6];
  const float* Wih   = (const float*)d_in[7];
  const float* Whh   = (const float*)d_in[8];
  const float* bih   = (const float*)d_in[9];
  const float* bhh   = (const float*)d_in[10];
  const float* wf    = (const float*)d_in[11];
  float* out = (float*)d_out;

  // workspace layout
  unsigned short* agg16  = (unsigned short*)d_ws;              // N_PAD*HID
  unsigned short* h16    = agg16 + (size_t)N_PAD*HID;          // N_PAD*HID
  unsigned short* srel16 = h16 + (size_t)N_PAD*HID;            // REL_VOCAB*HID
  unsigned short* re16   = srel16 + REL_VOCAB*HID;             // REL_VOCAB*HID
  unsigned short* pkWh   = re16 + REL_VOCAB*HID;               // 2*4096
  unsigned short* pkWih  = pkWh  + 2*4096;                     // 2*12288
  unsigned short* pkWhh  = pkWih + 2*12288;                    // 2*12288
  unsigned short* pkWs   = pkWhh + 2*12288;                    // 2048
  float* hrW1      = (float*)(pkWs + 2048);                    // REL_VOCAB*ATTN
  uint2* tmp       = (uint2*)(hrW1 + REL_VOCAB*ATTN);          // N_SLOT uint2
  unsigned int* pairP = (unsigned int*)(tmp + N_SLOT);         // N_SLOT uint
  int*   startArr  = (int*)(pairP + N_SLOT);                   // NCB*CBN
  int*   endArr    = startArr + NCB*CBN;                       // NCB*CBN
  int*   gcursor   = endArr + NCB*CBN;                         // 256 (pad)

  // ---- two-pass bucket sort of edges by obj ----
  k_izero<<<1, 256, 0, stream>>>(gcursor, 256);
  k_part<<<(N_EDGE + ACHUNK - 1)/ACHUNK, 256, 0, stream>>>(edges, gcursor, tmp);
  k_bsort2<<<NCB, 256, 0, stream>>>(tmp, gcursor, pairP, startArr, endArr);

  // ---- per-relation tables + packed bf16 weights ----
  k_pre<<<(REL_VOCAB*64+255)/256, 256, 0, stream>>>(re, Wr, ww, wb, srel16, re16, hrW1);
  k_wt<<<(116*64+255)/256, 256, 0, stream>>>(Wh, Wih, Whh, Ws, pkWh, pkWih, pkWhh, pkWs);

  const int NB_NODE2 = (N_NODE + 63) / 64;

  // ---- layer 0 ----
  k_agg0<<<(N_NODE*64)/256, 256, 0, stream>>>(startArr, endArr, pairP, srel16, agg16);
  k_node2<0><<<NB_NODE2, 256, 0, stream>>>(agg16, h16,
        pkWh, pkWih, pkWhh, bih, bhh, h16, wf, out, 0);

  // ---- layer 1 (fused alpha + aggregate, wave per node) ----
  k_fuse2<<<(N_NODE*64)/256, 256, 0, stream>>>(startArr, endArr, pairP,
        h16, hrW1, pkWs, ww + ATTN, wb + 1, re16, agg16);
  k_node2<1><<<NB_NODE2, 256, 0, stream>>>(agg16, h16,
        pkWh + 4096, pkWih + 12288, pkWhh + 12288, bih + 3*HID, bhh + 3*HID,
        h16, wf, out, 1);
}

// Round 14
// 199.791 us; speedup vs baseline: 1.0991x; 1.0137x over previous
//
#include <hip/hip_runtime.h>

#define N_NODE 100000
#define N_PAD  100064            // padded rows for OOB-safe fragment loads
#define N_EDGE 1000000
#define HID 64
#define ATTN 32
#define REL_VOCAB 2005

#define CBSHIFT 9
#define CBN    512               // nodes per coarse bucket
#define NCB    196               // ceil(N_NODE/CBN)
#define MAXCB  8192              // slots per bucket region (mean 5120, +43σ)
#define LCAP   6400              // LDS sort capacity (mean +18σ)
#define N_SLOT (NCB*MAXCB)       // 1,605,632 padded slots
#define ACHUNK 4096              // edges per k_part block

typedef short  bf16x8 __attribute__((ext_vector_type(8)));
typedef float  f32x4  __attribute__((ext_vector_type(4)));

__device__ __forceinline__ float sigf(float x){ return 1.0f/(1.0f+__expf(-x)); }
__device__ __forceinline__ float bf2f(unsigned short u){
  return __uint_as_float(((unsigned int)u) << 16);
}
__device__ __forceinline__ unsigned short f2bf(float f){  // RNE
  unsigned int x = __float_as_uint(f);
  x += 0x7fffu + ((x >> 16) & 1u);
  return (unsigned short)(x >> 16);
}

__device__ __forceinline__ float dot64(const float4* a, const float4* __restrict__ w){
  float s0=0.f,s1=0.f,s2=0.f,s3=0.f;
  #pragma unroll
  for (int i=0;i<16;i++){
    float4 av=a[i]; float4 wv=w[i];
    s0=fmaf(av.x,wv.x,s0); s1=fmaf(av.y,wv.y,s1);
    s2=fmaf(av.z,wv.z,s2); s3=fmaf(av.w,wv.w,s3);
  }
  return (s0+s1)+(s2+s3);
}

// ---- per-relation precompute, wave-parallel: one wave per relation ----
__global__ void __launch_bounds__(256, 4) k_pre(
    const float* __restrict__ re, const float* __restrict__ Wr,
    const float* __restrict__ ww, const float* __restrict__ wb,
    unsigned short* __restrict__ srel16, unsigned short* __restrict__ re16,
    float* __restrict__ hrW1)
{
  int w = (blockIdx.x*blockDim.x + threadIdx.x) >> 6;
  int l = threadIdx.x & 63;
  if (w >= REL_VOCAB) return;
  const int r = w;
  const int j = l & 31;
  const bool hi = (l >= 32);

  float4 ev[16];
  const float4* ep = (const float4*)(re + (size_t)(hi ? REL_VOCAB + r : r)*HID);
  #pragma unroll
  for (int i=0;i<16;i++) ev[i]=ep[i];

  const float4* wrow = (const float4*)(Wr + (size_t)(hi ? ATTN + j : j)*HID);
  float d = dot64(ev, wrow);

  if (hi) hrW1[r*ATTN + j] = d;

  float p = hi ? 0.f : fmaxf(d, 0.f) * ww[j];
  p += __shfl_xor(p, 1);
  p += __shfl_xor(p, 2);
  p += __shfl_xor(p, 4);
  p += __shfl_xor(p, 8);
  p += __shfl_xor(p, 16);
  p += __shfl_xor(p, 32);
  float alpha = sigf(p + wb[0]);

  float e0l = re[(size_t)r*HID + l];
  float e1l = re[(size_t)(REL_VOCAB + r)*HID + l];
  srel16[r*HID + l] = f2bf(alpha * e0l);
  re16[r*HID + l]   = f2bf(e1l);
}

__global__ void k_izero(int* __restrict__ p, int n){
  int i = blockIdx.x*blockDim.x + threadIdx.x;
  if (i < n) p[i] = 0;
}

// ---- weight pack into bf16 MFMA B-fragment order ----
__global__ void k_wt(const float* __restrict__ Wh, const float* __restrict__ Wih,
                     const float* __restrict__ Whh, const float* __restrict__ Ws,
                     unsigned short* __restrict__ pkWh, unsigned short* __restrict__ pkWih,
                     unsigned short* __restrict__ pkWhh, unsigned short* __restrict__ pkWs)
{
  int tid = blockIdx.x*blockDim.x + threadIdx.x;
  if (tid >= 116*64) return;
  int rec = tid >> 6, l = tid & 63;
  const float* src; unsigned short* dst; int tile, c;
  if (rec < 16){
    int li = rec >> 3, q = rec & 7; tile = q >> 1; c = q & 1;
    src = Wh + li*4096;
    dst = pkWh + (size_t)((li*8 + q)*64 + l)*8;
  } else if (rec < 64){
    int q2 = rec - 16; int li = q2 / 24, q = q2 % 24; tile = q >> 1; c = q & 1;
    src = Wih + li*12288;
    dst = pkWih + (size_t)((li*24 + q)*64 + l)*8;
  } else if (rec < 112){
    int q2 = rec - 64; int li = q2 / 24, q = q2 % 24; tile = q >> 1; c = q & 1;
    src = Whh + li*12288;
    dst = pkWhh + (size_t)((li*24 + q)*64 + l)*8;
  } else {
    int q = rec - 112; tile = q >> 1; c = q & 1;
    src = Ws + ATTN*HID;                       // layer-1 Ws only
    dst = pkWs + (size_t)(q*64 + l)*8;
  }
  int row = tile*16 + (l&15);
  int k0  = c*32 + (l>>4)*8;
  #pragma unroll
  for (int j=0;j<8;j++) dst[j] = f2bf(src[row*64 + k0 + j]);
}

// ---- pass A: block-level partition into 196 coarse buckets ----
__global__ void __launch_bounds__(256, 4) k_part(
    const int* __restrict__ edges, int* __restrict__ gcursor,
    uint2* __restrict__ tmp)
{
  __shared__ int hcnt[NCB];
  __shared__ int hbase[NCB];
  __shared__ int hcur[NCB];
  const int t = threadIdx.x;
  const int base = blockIdx.x * ACHUNK;
  const int nE = min(ACHUNK, N_EDGE - base);

  if (t < NCB){ hcnt[t] = 0; }
  __syncthreads();

  unsigned pk[16]; int bb[16], lo[16];
  const int2* e2 = (const int2*)edges;
  #pragma unroll
  for (int j=0;j<16;j++){
    int idx = j*256 + t;
    if (idx < nE){
      int e = base + idx;
      int rel = e2[e*3+1].x;
      int2 so = e2[e*3+2];
      pk[j] = ((unsigned)rel << 17) | (unsigned)so.x;
      bb[j] = so.y >> CBSHIFT;
      lo[j] = so.y & (CBN-1);
      atomicAdd(&hcnt[bb[j]], 1);
    } else bb[j] = -1;
  }
  __syncthreads();
  if (t < NCB){
    hbase[t] = (hcnt[t] > 0) ? atomicAdd(&gcursor[t], hcnt[t]) : 0;
    hcur[t] = 0;
  }
  __syncthreads();
  #pragma unroll
  for (int j=0;j<16;j++){
    if (bb[j] >= 0){
      int pos = hbase[bb[j]] + atomicAdd(&hcur[bb[j]], 1);
      if (pos < MAXCB)
        tmp[(size_t)bb[j]*MAXCB + pos] = make_uint2(pk[j], (unsigned)lo[j]);
    }
  }
}

// ---- pass B: in-bucket counting sort, one block per coarse bucket ----
__global__ void __launch_bounds__(256, 2) k_bsort2(
    const uint2* __restrict__ tmp, const int* __restrict__ gcursor,
    unsigned int* __restrict__ pairP, int* __restrict__ startArr,
    int* __restrict__ endArr)
{
  __shared__ int lcnt[CBN];
  __shared__ int lsc[CBN];
  __shared__ int lcur[CBN];
  __shared__ unsigned int lout[LCAP];
  const int b = blockIdx.x, t = threadIdx.x;
  const int base = b*MAXCB;
  const int size = min(gcursor[b], LCAP);

  lcnt[t] = 0; lcnt[256+t] = 0;
  __syncthreads();
  for (int i=t; i<size; i+=256)
    atomicAdd(&lcnt[tmp[base+i].y], 1);
  __syncthreads();

  int cA = lcnt[t], cB = lcnt[256+t];
  lsc[t] = cA; lsc[256+t] = cB;
  __syncthreads();
  #pragma unroll
  for (int off=1; off<256; off<<=1){
    int vA = (t>=off) ? lsc[t-off] : 0;
    int vB = (t>=off) ? lsc[256+t-off] : 0;
    __syncthreads();
    lsc[t] += vA; lsc[256+t] += vB;
    __syncthreads();
  }
  int totA = lsc[255];
  __syncthreads();
  lsc[256+t] += totA;
  __syncthreads();

  {
    int inclA = lsc[t], exclA = inclA - cA;
    lcur[t] = exclA;
    int n = b*CBN + t;
    if (n < N_NODE){ startArr[n] = base + exclA; endArr[n] = base + inclA; }
    int inclB = lsc[256+t], exclB = inclB - cB;
    lcur[256+t] = exclB;
    int n2 = b*CBN + 256 + t;
    if (n2 < N_NODE){ startArr[n2] = base + exclB; endArr[n2] = base + inclB; }
  }
  __syncthreads();

  for (int i=t; i<size; i+=256){
    uint2 p = tmp[base+i];
    int pos = atomicAdd(&lcur[p.y], 1);
    lout[pos] = p.x;
  }
  __syncthreads();
  for (int i=t; i<size; i+=256)
    pairP[base+i] = lout[i];
}

// ---- layer-0 aggregation: wave per node (bf16 table) -> bf16 agg ----
__global__ void k_agg0(const int* __restrict__ startArr, const int* __restrict__ endArr,
                       const unsigned int* __restrict__ pairP,
                       const unsigned short* __restrict__ srel16,
                       unsigned short* __restrict__ agg16)
{
  int t = blockIdx.x*blockDim.x + threadIdx.x;
  int n = __builtin_amdgcn_readfirstlane(t >> 6);
  int k = t & 63;
  if (n >= N_NODE) return;
  int b = startArr[n], e_ = endArr[n];
  float acc = 0.f;
  int i = b;
  for (; i+3 < e_; i += 4){
    int r0=pairP[i]>>17, r1=pairP[i+1]>>17, r2=pairP[i+2]>>17, r3=pairP[i+3]>>17;
    float v0=bf2f(srel16[r0*HID+k]), v1=bf2f(srel16[r1*HID+k]);
    float v2=bf2f(srel16[r2*HID+k]), v3=bf2f(srel16[r3*HID+k]);
    acc += v0; acc += v1; acc += v2; acc += v3;
  }
  for (; i < e_; ++i) acc += bf2f(srel16[(pairP[i]>>17)*HID + k]);
  agg16[(size_t)n*HID + k] = f2bf(acc);
}

// ---- fused layer-1 edge phase, wave per NODE ----
// per 16-edge chunk: alpha via 4x mfma_16x16x32 (h16 rows as A-frags, lane
// lr = edge, CLAMPED so masked lanes duplicate a valid row -> L1 hit, no
// garbage gathers), then a batched channel-parallel walk: issue all 16x2 row
// loads into compile-time-indexed register arrays, then a 4-accumulator fma
// tree (no serial chain, no break -> full unroll).
__global__ void __launch_bounds__(256, 4) k_fuse2(
    const int* __restrict__ startArr, const int* __restrict__ endArr,
    const unsigned int* __restrict__ pairP,
    const unsigned short* __restrict__ h16,
    const float* __restrict__ hrW1, const unsigned short* __restrict__ pkWs,
    const float* __restrict__ ww1, const float* __restrict__ wb1,
    const unsigned short* __restrict__ re16,
    unsigned short* __restrict__ agg16)
{
  const int t = threadIdx.x;
  const int w = t >> 6, l = t & 63;
  const int lr = l & 15, lg = l >> 4;
  const int n = __builtin_amdgcn_readfirstlane(blockIdx.x*4 + w);
  if (n >= N_NODE) return;
  const int b = startArr[n], e_ = endArr[n];

  // chunk-invariant operands (L1-resident)
  bf16x8 b00 = *(const bf16x8*)(pkWs + (size_t)(0*64 + l)*8);
  bf16x8 b01 = *(const bf16x8*)(pkWs + (size_t)(1*64 + l)*8);
  bf16x8 b10 = *(const bf16x8*)(pkWs + (size_t)(2*64 + l)*8);
  bf16x8 b11 = *(const bf16x8*)(pkWs + (size_t)(3*64 + l)*8);
  const float wlo = ww1[lr], whi = ww1[16 + lr];
  const float bias = wb1[0];

  float acc = 0.f;
  for (int c = b; c < e_; c += 16){
    const int nv = e_ - c;                       // wave-uniform; >=1

    // edge lr of this chunk, clamped: masked lanes re-read a valid slot
    unsigned pe = pairP[c + min(lr, nv-1)];
    int subA = (int)(pe & 0x1FFFFu);
    bf16x8 a0 = *(const bf16x8*)(h16 + (size_t)subA*HID + lg*8);
    bf16x8 a1 = *(const bf16x8*)(h16 + (size_t)subA*HID + 32 + lg*8);

    f32x4 acc0 = {0.f,0.f,0.f,0.f}, acc1 = {0.f,0.f,0.f,0.f};
    acc0 = __builtin_amdgcn_mfma_f32_16x16x32_bf16(a0, b00, acc0, 0,0,0);
    acc0 = __builtin_amdgcn_mfma_f32_16x16x32_bf16(a1, b01, acc0, 0,0,0);
    acc1 = __builtin_amdgcn_mfma_f32_16x16x32_bf16(a0, b10, acc1, 0,0,0);
    acc1 = __builtin_amdgcn_mfma_f32_16x16x32_bf16(a1, b11, acc1, 0,0,0);

    // alpha epilogue: after reduce, all 16 lanes of group lg hold alpha of
    // edge c + lg*4 + r in s[r]
    float s[4];
    #pragma unroll
    for (int r=0;r<4;r++){
      int pe_er = __shfl((int)pe, lg*4 + r);
      int rel = ((unsigned)pe_er) >> 17;
      float v0 = fmaxf(acc0[r] + hrW1[rel*ATTN + lr],      0.f);
      float v1 = fmaxf(acc1[r] + hrW1[rel*ATTN + 16 + lr], 0.f);
      float p = fmaf(v0, wlo, v1*whi);
      p += __shfl_xor(p, 1);
      p += __shfl_xor(p, 2);
      p += __shfl_xor(p, 4);
      p += __shfl_xor(p, 8);
      s[r] = sigf(p + bias);
    }

    // batched walk: all loads issued first (compile-time reg indices),
    // then a 4-accumulator reduction. Rows are L1-hot from phase 1.
    float hvv[16], rvv[16], alv[16];
    #pragma unroll
    for (int e=0; e<16; ++e){
      int pe_e = __shfl((int)pe, e);             // clamped -> valid row
      float al = __shfl(s[e & 3], (e >> 2) * 16);
      int sub_e = pe_e & 0x1FFFF;
      int rel_e = ((unsigned)pe_e) >> 17;
      alv[e] = (e < nv) ? al : 0.f;
      hvv[e] = bf2f(h16[(size_t)sub_e*HID + l]);
      rvv[e] = bf2f(re16[rel_e*HID + l]);
    }
    float a0s=0.f, a1s=0.f, a2s=0.f, a3s=0.f;
    #pragma unroll
    for (int e=0; e<16; e+=4){
      a0s = fmaf(alv[e+0], hvv[e+0]+rvv[e+0], a0s);
      a1s = fmaf(alv[e+1], hvv[e+1]+rvv[e+1], a1s);
      a2s = fmaf(alv[e+2], hvv[e+2]+rvv[e+2], a2s);
      a3s = fmaf(alv[e+3], hvv[e+3]+rvv[e+3], a3s);
    }
    acc += (a0s+a1s)+(a2s+a3s);
  }
  agg16[(size_t)n*HID + l] = f2bf(acc);
}

// ---- MFMA node phase: 64 nodes/block, wave w owns nodes w*16..w*16+15 ----
template<int HAS_H0>
__global__ void __launch_bounds__(256, 2) k_node2(
    const unsigned short* __restrict__ agg16,
    const unsigned short* __restrict__ h16,
    const unsigned short* __restrict__ pkWh,
    const unsigned short* __restrict__ pkWih,
    const unsigned short* __restrict__ pkWhh,
    const float* __restrict__ bih, const float* __restrict__ bhh,
    unsigned short* __restrict__ h16_out,
    const float* __restrict__ wf, float* __restrict__ score, int mode)
{
  __shared__ unsigned short xlds[4096];   // 4 waves x [16 rows][64 cols] bf16, swizzled

  const int t  = threadIdx.x;
  const int w  = t >> 6, l = t & 63;
  const int lr = l & 15;                  // fragment row/col
  const int lg = l >> 4;                  // k-group
  const int n0 = blockIdx.x * 64;
  const int rowA = n0 + w*16 + lr;

  bf16x8 aA0 = *(const bf16x8*)(agg16 + (size_t)rowA*HID + lg*8);
  bf16x8 aA1 = *(const bf16x8*)(agg16 + (size_t)rowA*HID + 32 + lg*8);
  bf16x8 hA0, hA1;
  if (HAS_H0){
    hA0 = *(const bf16x8*)(h16 + (size_t)rowA*HID + lg*8);
    hA1 = *(const bf16x8*)(h16 + (size_t)rowA*HID + 32 + lg*8);
  }

  float bir[4],biz[4],bin[4],bhr[4],bhz[4],bhn[4],wfv[4];
  #pragma unroll
  for (int nt=0;nt<4;nt++){
    int ch = nt*16 + lr;
    bir[nt]=bih[ch]; biz[nt]=bih[64+ch]; bin[nt]=bih[128+ch];
    bhr[nt]=bhh[ch]; bhz[nt]=bhh[64+ch]; bhn[nt]=bhh[128+ch];
    wfv[nt]=wf[ch];
  }

  // ---- X = relu(agg @ Wh^T) ----
  #pragma unroll
  for (int nt=0;nt<4;nt++){
    f32x4 acc = {0.f,0.f,0.f,0.f};
    bf16x8 b0 = *(const bf16x8*)(pkWh + (size_t)((nt*2+0)*64 + l)*8);
    bf16x8 b1 = *(const bf16x8*)(pkWh + (size_t)((nt*2+1)*64 + l)*8);
    acc = __builtin_amdgcn_mfma_f32_16x16x32_bf16(aA0, b0, acc, 0,0,0);
    acc = __builtin_amdgcn_mfma_f32_16x16x32_bf16(aA1, b1, acc, 0,0,0);
    #pragma unroll
    for (int r=0;r<4;r++){
      int m = lg*4 + r, col = nt*16 + lr;
      xlds[w*1024 + m*64 + (col ^ ((m&7)<<3))] = f2bf(fmaxf(acc[r], 0.f));
    }
  }
  __syncthreads();

  const int xbase = w*1024 + lr*64;
  const int sw = (lr&7)<<3;
  bf16x8 xA0 = *(const bf16x8*)&xlds[xbase + ((lg*8)      ^ sw)];
  bf16x8 xA1 = *(const bf16x8*)&xlds[xbase + ((32 + lg*8) ^ sw)];

  // ---- gate passes ----
  float rv[16], zv[16], hv[16];
  #pragma unroll
  for (int g=0; g<2; ++g){               // g=0: r-gate, g=1: z-gate
    #pragma unroll
    for (int nt=0;nt<4;nt++){
      int gt = g*4 + nt;
      f32x4 ai = {0.f,0.f,0.f,0.f};
      bf16x8 bi0 = *(const bf16x8*)(pkWih + (size_t)((gt*2+0)*64 + l)*8);
      bf16x8 bi1 = *(const bf16x8*)(pkWih + (size_t)((gt*2+1)*64 + l)*8);
      ai = __builtin_amdgcn_mfma_f32_16x16x32_bf16(xA0, bi0, ai, 0,0,0);
      ai = __builtin_amdgcn_mfma_f32_16x16x32_bf16(xA1, bi1, ai, 0,0,0);
      f32x4 ah = {0.f,0.f,0.f,0.f};
      if (HAS_H0){
        bf16x8 bh0 = *(const bf16x8*)(pkWhh + (size_t)((gt*2+0)*64 + l)*8);
        bf16x8 bh1 = *(const bf16x8*)(pkWhh + (size_t)((gt*2+1)*64 + l)*8);
        ah = __builtin_amdgcn_mfma_f32_16x16x32_bf16(hA0, bh0, ah, 0,0,0);
        ah = __builtin_amdgcn_mfma_f32_16x16x32_bf16(hA1, bh1, ah, 0,0,0);
      }
      #pragma unroll
      for (int r=0;r<4;r++){
        float bi_ = (g==0) ? bir[nt] : biz[nt];
        float bh_ = (g==0) ? bhr[nt] : bhz[nt];
        float v = sigf(ai[r] + bi_ + ah[r] + bh_);
        if (g==0) rv[nt*4+r] = v; else zv[nt*4+r] = v;
      }
    }
  }
  #pragma unroll
  for (int nt=0;nt<4;nt++){              // n-gate + GRU blend
    int gt = 8 + nt;
    f32x4 ai = {0.f,0.f,0.f,0.f};
    bf16x8 bi0 = *(const bf16x8*)(pkWih + (size_t)((gt*2+0)*64 + l)*8);
    bf16x8 bi1 = *(const bf16x8*)(pkWih + (size_t)((gt*2+1)*64 + l)*8);
    ai = __builtin_amdgcn_mfma_f32_16x16x32_bf16(xA0, bi0, ai, 0,0,0);
    ai = __builtin_amdgcn_mfma_f32_16x16x32_bf16(xA1, bi1, ai, 0,0,0);
    f32x4 ah = {0.f,0.f,0.f,0.f};
    if (HAS_H0){
      bf16x8 bh0 = *(const bf16x8*)(pkWhh + (size_t)((gt*2+0)*64 + l)*8);
      bf16x8 bh1 = *(const bf16x8*)(pkWhh + (size_t)((gt*2+1)*64 + l)*8);
      ah = __builtin_amdgcn_mfma_f32_16x16x32_bf16(hA0, bh0, ah, 0,0,0);
      ah = __builtin_amdgcn_mfma_f32_16x16x32_bf16(hA1, bh1, ah, 0,0,0);
    }
    #pragma unroll
    for (int r=0;r<4;r++){
      float gin = ai[r] + bin[nt];
      float ghn = ah[r] + bhn[nt];
      float rr  = rv[nt*4+r];
      float nn  = tanhf(fmaf(rr, ghn, gin));
      float z   = zv[nt*4+r];
      float h0v = 0.f;
      if (HAS_H0)
        h0v = bf2f(h16[(size_t)(n0 + w*16 + lg*4 + r)*HID + nt*16 + lr]);
      hv[nt*4+r] = (1.f - z)*nn + z*h0v;
    }
  }

  if (mode == 0){
    __syncthreads();
    #pragma unroll
    for (int nt=0;nt<4;nt++)
      #pragma unroll
      for (int r=0;r<4;r++){
        int m = lg*4 + r, col = nt*16 + lr;
        xlds[w*1024 + m*64 + (col ^ ((m&7)<<3))] = f2bf(hv[nt*4+r]);
      }
    __syncthreads();
    int rr2 = l >> 2, cc = l & 3;
    int n = n0 + w*16 + rr2;
    if (n < N_NODE){
      int base = w*1024 + rr2*64, s2 = (rr2&7)<<3;
      bf16x8 v0 = *(const bf16x8*)&xlds[base + ((cc*16)     ^ s2)];
      bf16x8 v1 = *(const bf16x8*)&xlds[base + ((cc*16 + 8) ^ s2)];
      *(bf16x8*)(h16_out + (size_t)n*HID + cc*16)     = v0;
      *(bf16x8*)(h16_out + (size_t)n*HID + cc*16 + 8) = v1;
    }
  } else {
    #pragma unroll
    for (int r=0;r<4;r++){
      float p = 0.f;
      #pragma unroll
      for (int nt=0;nt<4;nt++) p = fmaf(hv[nt*4+r], wfv[nt], p);
      p += __shfl_xor(p, 1);
      p += __shfl_xor(p, 2);
      p += __shfl_xor(p, 4);
      p += __shfl_xor(p, 8);
      if (lr == 0){
        int n = n0 + w*16 + lg*4 + r;
        if (n < N_NODE) score[n] = p;
      }
    }
  }
}

extern "C" void kernel_launch(void* const* d_in, const int* in_sizes, int n_in,
                              void* d_out, int out_size, void* d_ws, size_t ws_size,
                              hipStream_t stream)
{
  const int*   edges = (const int*)  d_in[0];
  const float* re    = (const float*)d_in[1];
  const float* Ws    = (const float*)d_in[2];
  const float* Wr    = (const float*)d_in[3];
  const float* ww    = (const float*)d_in[4];
  const float* wb    = (const float*)d_in[5];
  const float* Wh    = (const float*)d_in[6];
  const float* Wih   = (const float*)d_in[7];
  const float* Whh   = (const float*)d_in[8];
  const float* bih   = (const float*)d_in[9];
  const float* bhh   = (const float*)d_in[10];
  const float* wf    = (const float*)d_in[11];
  float* out = (float*)d_out;

  // workspace layout
  unsigned short* agg16  = (unsigned short*)d_ws;              // N_PAD*HID
  unsigned short* h16    = agg16 + (size_t)N_PAD*HID;          // N_PAD*HID
  unsigned short* srel16 = h16 + (size_t)N_PAD*HID;            // REL_VOCAB*HID
  unsigned short* re16   = srel16 + REL_VOCAB*HID;             // REL_VOCAB*HID
  unsigned short* pkWh   = re16 + REL_VOCAB*HID;               // 2*4096
  unsigned short* pkWih  = pkWh  + 2*4096;                     // 2*12288
  unsigned short* pkWhh  = pkWih + 2*12288;                    // 2*12288
  unsigned short* pkWs   = pkWhh + 2*12288;                    // 2048
  float* hrW1      = (float*)(pkWs + 2048);                    // REL_VOCAB*ATTN
  uint2* tmp       = (uint2*)(hrW1 + REL_VOCAB*ATTN);          // N_SLOT uint2
  unsigned int* pairP = (unsigned int*)(tmp + N_SLOT);         // N_SLOT uint
  int*   startArr  = (int*)(pairP + N_SLOT);                   // NCB*CBN
  int*   endArr    = startArr + NCB*CBN;                       // NCB*CBN
  int*   gcursor   = endArr + NCB*CBN;                         // 256 (pad)

  // ---- two-pass bucket sort of edges by obj ----
  k_izero<<<1, 256, 0, stream>>>(gcursor, 256);
  k_part<<<(N_EDGE + ACHUNK - 1)/ACHUNK, 256, 0, stream>>>(edges, gcursor, tmp);
  k_bsort2<<<NCB, 256, 0, stream>>>(tmp, gcursor, pairP, startArr, endArr);

  // ---- per-relation tables + packed bf16 weights ----
  k_pre<<<(REL_VOCAB*64+255)/256, 256, 0, stream>>>(re, Wr, ww, wb, srel16, re16, hrW1);
  k_wt<<<(116*64+255)/256, 256, 0, stream>>>(Wh, Wih, Whh, Ws, pkWh, pkWih, pkWhh, pkWs);

  const int NB_NODE2 = (N_NODE + 63) / 64;

  // ---- layer 0 ----
  k_agg0<<<(N_NODE*64)/256, 256, 0, stream>>>(startArr, endArr, pairP, srel16, agg16);
  k_node2<0><<<NB_NODE2, 256, 0, stream>>>(agg16, h16,
        pkWh, pkWih, pkWhh, bih, bhh, h16, wf, out, 0);

  // ---- layer 1 (fused alpha + aggregate, wave per node) ----
  k_fuse2<<<(N_NODE*64)/256, 256, 0, stream>>>(startArr, endArr, pairP,
        h16, hrW1, pkWs, ww + ATTN, wb + 1, re16, agg16);
  k_node2<1><<<NB_NODE2, 256, 0, stream>>>(agg16, h16,
        pkWh + 4096, pkWih + 12288, pkWhh + 12288, bih + 3*HID, bhh + 3*HID,
        h16, wf, out, 1);
}